// Round 14
// baseline (242.321 us; speedup 1.0000x reference)
//
#include <hip/hip_runtime.h>

// PK_RNN: GRU + pharmacokinetic scan, B=2048 x T=256, HID=32.
// Round 13: base = round-12 green (230.2us total; 64 lanes/batch, column-split
// packed-f32x2 gate dots, shfl_xor gate swaps, DPP kv reduce). Round-12 showed
// VALUBusy 78->52% at unchanged time => latency-bound with spare issue slack.
// Single change: FUSE the loss accumulation into the scan. kk/vv/concn are
// lane-uniform per step; accumulate the 6 loss partials redundantly on all
// lanes (~10 VALU/step, off the critical chain), write 6 floats/batch to ws,
// finalize with a 1-block kernel. Eliminates loss_partial's ~100MB re-read
// (~20us) and one launch. Fallback to the old path if ws < 48KB.

constexpr int Bn = 2048, Tn = 256;
constexpr int HID = 32, CONT = 40, EMB = 8;
constexpr int VOCAB = 829, CODES = 32;
constexpr int BT = Bn * Tn;

typedef float f32x2 __attribute__((ext_vector_type(2)));

__device__ __forceinline__ float frcp(float x) { return __builtin_amdgcn_rcpf(x); }

// lane j gets (its value + partner(j^32)'s value) -- proven green primitive
__device__ __forceinline__ float swap_add(float x) {
  return x + __shfl_xor(x, 32, 64);
}

// x + dpp_shifted(x), old=0, all rows/banks enabled, bound_ctrl=1 (0-fill)
template <int CTRL>
__device__ __forceinline__ float dpp_add(float x) {
  int y = __builtin_amdgcn_update_dpp(0, __float_as_int(x), CTRL, 0xf, 0xf, true);
  return x + __int_as_float(y);
}

// ---------------- recurrent kernel ----------------
template <bool FUSE>
__global__ __launch_bounds__(256, 2) void rnn_kernel(
    const float* __restrict__ cont, const int* __restrict__ cat,
    const float* __restrict__ lb, const float* __restrict__ dose,
    const float* __restrict__ tdp, const float* __restrict__ embed,
    const float* __restrict__ W_ih, const float* __restrict__ W_hh,
    const float* __restrict__ b_ih, const float* __restrict__ b_hh,
    const float* __restrict__ W_out, const float* __restrict__ b_out,
    const float* __restrict__ vel, const float* __restrict__ vfw,
    float* __restrict__ part, float* __restrict__ out) {
  __shared__ __attribute__((aligned(16))) float esh[VOCAB * EMB];  // 26528 B
  __shared__ __attribute__((aligned(16))) float ebl[4][64][EMB];   //  8192 B
  __shared__ __attribute__((aligned(16))) float hsh[4][HID];       //   512 B

  const int tid = threadIdx.x;
  const int wv = tid >> 6;    // wave id in block = batch-in-block 0..3
  const int j = tid & 63;     // lane
  const int u = j & 31;       // hidden unit owned by this lane
  const int half = j >> 5;    // column-half this lane covers
  const int b = blockIdx.x * 4 + wv;
  const int base = b * Tn;

  // embedding table -> LDS (once); only cross-wave shared data
  for (int i = tid; i < VOCAB * EMB; i += 256) esh[i] = embed[i];
  __syncthreads();

  // ---- loop-invariant weights into registers (packed as f32x2 pairs) ----
  f32x2 wxr2[12], wxz2[12], wxn2[12];
  {
    float tr[24], tz[24], tn_[24];
    const float* Wr = W_ih + (size_t)u * 49;
    const float* Wz = W_ih + (size_t)(HID + u) * 49;
    const float* Wn = W_ih + (size_t)(2 * HID + u) * 49;
    const int eo = half * 4;
    const int co = 8 + half * 20;
#pragma unroll
    for (int k = 0; k < 4; k++) { tr[k] = Wr[eo + k]; tz[k] = Wz[eo + k]; tn_[k] = Wn[eo + k]; }
#pragma unroll
    for (int k = 0; k < 20; k++) {
      tr[4 + k] = Wr[co + k]; tz[4 + k] = Wz[co + k]; tn_[4 + k] = Wn[co + k];
    }
#pragma unroll
    for (int k = 0; k < 12; k++) {
      wxr2[k] = (f32x2){tr[2 * k], tr[2 * k + 1]};
      wxz2[k] = (f32x2){tz[2 * k], tz[2 * k + 1]};
      wxn2[k] = (f32x2){tn_[2 * k], tn_[2 * k + 1]};
    }
  }
  const float wvr = half ? W_ih[(size_t)u * 49 + 48] : 0.0f;
  const float wvz = half ? W_ih[(size_t)(HID + u) * 49 + 48] : 0.0f;
  const float wvn = half ? W_ih[(size_t)(2 * HID + u) * 49 + 48] : 0.0f;
  f32x2 whr2[8], whz2[8], whn2[8];
#pragma unroll
  for (int k = 0; k < 8; k++) {
    whr2[k] = (f32x2){W_hh[(size_t)u * HID + half * 16 + 2 * k],
                      W_hh[(size_t)u * HID + half * 16 + 2 * k + 1]};
    whz2[k] = (f32x2){W_hh[(size_t)(HID + u) * HID + half * 16 + 2 * k],
                      W_hh[(size_t)(HID + u) * HID + half * 16 + 2 * k + 1]};
    whn2[k] = (f32x2){W_hh[(size_t)(2 * HID + u) * HID + half * 16 + 2 * k],
                      W_hh[(size_t)(2 * HID + u) * HID + half * 16 + 2 * k + 1]};
  }
  const float br = half ? 0.0f : (b_ih[u] + b_hh[u]);
  const float bz = half ? 0.0f : (b_ih[HID + u] + b_hh[HID + u]);
  const float bni = half ? 0.0f : b_ih[2 * HID + u];
  const float bnh = half ? 0.0f : b_hh[2 * HID + u];
  const float wkv = W_out[half * HID + u];
  const float bo0 = b_out[0], bo1 = b_out[1];

  hsh[wv][u] = 0.0f;
  float hj = 0.0f, tm = 0.0f, concn = 0.0f;
  float td_c = tdp[base], d_c = dose[base], lbp_c = 0.0f;

  // fused-loss state (lane-uniform redundant accumulation)
  float lmse = 0.f, lcnt = 0.f, lk0 = 0.f, lv0 = 0.f, ldk = 0.f, ldv = 0.f;
  float kprev = 0.f, vprev = 0.f;
  float vel0 = 0.f, vfw0 = 0.f;
  if (FUSE) { vel0 = vel[base]; vfw0 = vfw[base]; }

  // cont slice double buffer: 5 float4 = 20 floats at offset half*20
  float4 xA[5], xB[5];
  {
    const float4* c4 = reinterpret_cast<const float4*>(cont + (size_t)base * CONT + half * 20);
#pragma unroll
    for (int q = 0; q < 5; q++) xA[q] = c4[q];
  }

#define STEP(XC, XN, TT)                                                          \
  {                                                                               \
    const int t = (TT);                                                           \
    const int tn = (t + 1 < Tn) ? (t + 1) : t;                                    \
    /* (1) LDS reads first: e, then the 4 h reads */                              \
    const float4 e = *reinterpret_cast<const float4*>(&ebl[wv][t & 63][half * 4]);\
    const float4* h4 = reinterpret_cast<const float4*>(&hsh[wv][half * 16]);      \
    const float4 hv0 = h4[0];                                                     \
    const float4 hv1 = h4[1];                                                     \
    const float4 hv2 = h4[2];                                                     \
    const float4 hv3 = h4[3];                                                     \
    /* (2) global prefetches for t+1 */                                           \
    { const float4* c4 = reinterpret_cast<const float4*>(                         \
          cont + (size_t)(base + tn) * CONT + half * 20);                         \
      _Pragma("unroll") for (int q = 0; q < 5; q++) XN[q] = c4[q]; }              \
    const float td_n = tdp[base + tn];                                            \
    const float d_n = dose[base + tn];                                            \
    const float lbp_n = lb[base + tn - 1];                                        \
    /* (3) x-dots, f32x2-packed (v_pk_fma_f32) */                                 \
    f32x2 arv, azv, anv;                                                          \
    {                                                                             \
      const f32x2 e01 = (f32x2){e.x, e.y}, e23 = (f32x2){e.z, e.w};               \
      arv = wxr2[0] * e01 + wxr2[1] * e23;                                        \
      azv = wxz2[0] * e01 + wxz2[1] * e23;                                        \
      anv = wxn2[0] * e01 + wxn2[1] * e23;                                        \
      _Pragma("unroll") for (int q = 0; q < 5; q++) {                             \
        const float4 xv = XC[q];                                                  \
        const f32x2 x01 = (f32x2){xv.x, xv.y}, x23 = (f32x2){xv.z, xv.w};         \
        arv += wxr2[2 + 2 * q] * x01; arv += wxr2[3 + 2 * q] * x23;               \
        azv += wxz2[2 + 2 * q] * x01; azv += wxz2[3 + 2 * q] * x23;               \
        anv += wxn2[2 + 2 * q] * x01; anv += wxn2[3 + 2 * q] * x23;               \
      }                                                                           \
    }                                                                             \
    /* (4) h-dots, f32x2-packed */                                                \
    f32x2 grv, gzv, gnv;                                                          \
    {                                                                             \
      const f32x2 h01 = (f32x2){hv0.x, hv0.y}, h23 = (f32x2){hv0.z, hv0.w};       \
      const f32x2 h45 = (f32x2){hv1.x, hv1.y}, h67 = (f32x2){hv1.z, hv1.w};       \
      const f32x2 h89 = (f32x2){hv2.x, hv2.y}, hab = (f32x2){hv2.z, hv2.w};       \
      const f32x2 hcd = (f32x2){hv3.x, hv3.y}, hef = (f32x2){hv3.z, hv3.w};       \
      grv = whr2[0] * h01 + whr2[1] * h23;                                        \
      gzv = whz2[0] * h01 + whz2[1] * h23;                                        \
      gnv = whn2[0] * h01 + whn2[1] * h23;                                        \
      grv += whr2[2] * h45; grv += whr2[3] * h67;                                 \
      gzv += whz2[2] * h45; gzv += whz2[3] * h67;                                 \
      gnv += whn2[2] * h45; gnv += whn2[3] * h67;                                 \
      grv += whr2[4] * h89; grv += whr2[5] * hab;                                 \
      gzv += whz2[4] * h89; gzv += whz2[5] * hab;                                 \
      gnv += whn2[4] * h89; gnv += whn2[5] * hab;                                 \
      grv += whr2[6] * hcd; grv += whr2[7] * hef;                                 \
      gzv += whz2[6] * hcd; gzv += whz2[7] * hef;                                 \
      gnv += whn2[6] * hcd; gnv += whn2[7] * hef;                                 \
    }                                                                             \
    const float fmv = (lbp_c != 0.0f) ? 1.0f : 0.0f;                              \
    const float vfb = concn * (1.0f - fmv) + lbp_c * fmv;                         \
    const float ar = arv.x + arv.y + vfb * wvr;                                   \
    const float az = azv.x + azv.y + vfb * wvz;                                   \
    const float an = anv.x + anv.y + vfb * wvn;                                   \
    const float gr = grv.x + grv.y;                                               \
    const float gz = gzv.x + gzv.y;                                               \
    const float gn = gnv.x + gnv.y;                                               \
    const float sr = swap_add(ar + gr + br);                                      \
    const float sz = swap_add(az + gz + bz);                                      \
    const float sa = swap_add(an + bni);                                          \
    const float sg = swap_add(gn + bnh);                                          \
    const float r = frcp(1.0f + __expf(-sr));                                     \
    const float z = frcp(1.0f + __expf(-sz));                                     \
    const float pre = sa + r * sg;                                                \
    const float nv = 1.0f - 2.0f * frcp(__expf(2.0f * pre) + 1.0f);               \
    const float h2 = (1.0f - z) * nv + z * hj;                                    \
    hsh[wv][u] = h2;                                                              \
    hj = h2;                                                                      \
    /* kv reduce: DPP intra-32 tree + readlane broadcasts */                      \
    float s = h2 * wkv;                                                           \
    s = dpp_add<0x111>(s); /* row_shr:1 */                                        \
    s = dpp_add<0x112>(s); /* row_shr:2 */                                        \
    s = dpp_add<0x114>(s); /* row_shr:4 */                                        \
    s = dpp_add<0x118>(s); /* row_shr:8 */                                        \
    s = dpp_add<0x142>(s); /* row_bcast:15 -> lane31=sum(0:32), lane63=sum(32:64) */ \
    const float pk_s = __int_as_float(__builtin_amdgcn_readlane(__float_as_int(s), 31)); \
    const float pv_s = __int_as_float(__builtin_amdgcn_readlane(__float_as_int(s), 63)); \
    const float kk = __expf(pk_s + bo0);                                          \
    const float vv = __expf(pv_s + bo1);                                          \
    const float Aa = __expf(-kk * td_c);                                          \
    const float eD = __expf(-kk * d_c);                                           \
    const float Bq = frcp(kk) * (1.0f - eD) * __expf(-kk * (td_c - d_c));         \
    tm = tm * Aa + Bq;                                                            \
    concn = tm * frcp(vv + 1e-6f);                                                \
    if (j < 3) {                                                                  \
      const float val = (j == 0) ? kk : ((j == 1) ? vv : concn);                  \
      out[j * BT + base + t] = val;                                               \
    }                                                                             \
    if (FUSE) { /* lane-uniform loss accumulation, off critical chain */          \
      const float l_t = lb[base + t];                                             \
      const float m = (l_t != 0.0f) ? 1.0f : 0.0f;                                \
      const float dd = (concn - l_t) * m;                                         \
      lmse += dd * dd;                                                            \
      lcnt += m;                                                                  \
      if (t > 0) {                                                                \
        ldk += (kk - kprev) * (kk - kprev);                                       \
        ldv += (vv - vprev) * (vv - vprev);                                       \
      } else {                                                                    \
        lk0 = (vel0 - kk) * (vel0 - kk);                                          \
        lv0 = (vfw0 - vv) * (vfw0 - vv);                                          \
      }                                                                           \
      kprev = kk;                                                                 \
      vprev = vv;                                                                 \
    }                                                                             \
    td_c = td_n;                                                                  \
    d_c = d_n;                                                                    \
    lbp_c = lbp_n;                                                                \
  }

  for (int ch = 0; ch < Tn / 64; ++ch) {
    {  // per-wave embedding presum for this 64-step chunk: lane j handles t=ch*64+j
      const int4* cp4 =
          reinterpret_cast<const int4*>(cat + ((size_t)(base + ch * 64 + j)) * CODES);
      float a0 = 0.f, a1 = 0.f, a2 = 0.f, a3 = 0.f;
      float a4 = 0.f, a5 = 0.f, a6 = 0.f, a7 = 0.f;
#pragma unroll
      for (int q = 0; q < 8; q++) {
        const int4 c4 = cp4[q];
        {
          const float4* er = reinterpret_cast<const float4*>(esh + c4.x * EMB);
          const float4 r0 = er[0], r1 = er[1];
          a0 += r0.x; a1 += r0.y; a2 += r0.z; a3 += r0.w;
          a4 += r1.x; a5 += r1.y; a6 += r1.z; a7 += r1.w;
        }
        {
          const float4* er = reinterpret_cast<const float4*>(esh + c4.y * EMB);
          const float4 r0 = er[0], r1 = er[1];
          a0 += r0.x; a1 += r0.y; a2 += r0.z; a3 += r0.w;
          a4 += r1.x; a5 += r1.y; a6 += r1.z; a7 += r1.w;
        }
        {
          const float4* er = reinterpret_cast<const float4*>(esh + c4.z * EMB);
          const float4 r0 = er[0], r1 = er[1];
          a0 += r0.x; a1 += r0.y; a2 += r0.z; a3 += r0.w;
          a4 += r1.x; a5 += r1.y; a6 += r1.z; a7 += r1.w;
        }
        {
          const float4* er = reinterpret_cast<const float4*>(esh + c4.w * EMB);
          const float4 r0 = er[0], r1 = er[1];
          a0 += r0.x; a1 += r0.y; a2 += r0.z; a3 += r0.w;
          a4 += r1.x; a5 += r1.y; a6 += r1.z; a7 += r1.w;
        }
      }
      *reinterpret_cast<float4*>(&ebl[wv][j][0]) = make_float4(a0, a1, a2, a3);
      *reinterpret_cast<float4*>(&ebl[wv][j][4]) = make_float4(a4, a5, a6, a7);
    }
    __syncthreads();  // ordering insurance for presum -> STEP reads (4 total)
#pragma unroll 1
    for (int tl = 0; tl < 64; tl += 2) {
      STEP(xA, xB, ch * 64 + tl);
      STEP(xB, xA, ch * 64 + tl + 1);
    }
  }
#undef STEP

  if (FUSE) {
    // all 6 accumulators are lane-uniform; lanes 0..5 write one each
    const float v0s = (j == 0) ? lmse
                    : (j == 1) ? lcnt
                    : (j == 2) ? lk0
                    : (j == 3) ? lv0
                    : (j == 4) ? ldk : ldv;
    if (j < 6) part[b * 6 + j] = v0s;
  }
}

__device__ __forceinline__ void finalize_loss(const float s[6], float* out) {
  const float mse = s[0] / s[1];
  const float loss = mse + (s[2] / (float)Bn) * 1000.0f + (s[3] / (float)Bn) * 1000.0f +
                     (s[4] / (float)(Bn * (Tn - 1))) * 1000.0f +
                     (s[5] / (float)(Bn * (Tn - 1))) * 1000.0f;
  out[3 * BT] = loss;
  out[3 * BT + 1] = mse;
}

// finalize from 2048x6 per-batch partials (one block)
__global__ __launch_bounds__(256) void loss_final2_kernel(const float* __restrict__ part,
                                                          float* __restrict__ out) {
  float acc[6] = {0.f, 0.f, 0.f, 0.f, 0.f, 0.f};
  for (int i = threadIdx.x; i < Bn; i += 256) {
#pragma unroll
    for (int q = 0; q < 6; q++) acc[q] += part[i * 6 + q];
  }
#pragma unroll
  for (int q = 0; q < 6; q++) {
#pragma unroll
    for (int mm = 1; mm < 64; mm <<= 1) acc[q] += __shfl_xor(acc[q], mm, 64);
  }
  __shared__ float red[4][6];
  if ((threadIdx.x & 63) == 0) {
#pragma unroll
    for (int q = 0; q < 6; q++) red[threadIdx.x >> 6][q] = acc[q];
  }
  __syncthreads();
  if (threadIdx.x == 0) {
    float s[6];
#pragma unroll
    for (int q = 0; q < 6; q++) s[q] = red[0][q] + red[1][q] + red[2][q] + red[3][q];
    finalize_loss(s, out);
  }
}

// ws-free fallback: one block does the whole reduction (safety net only)
__global__ __launch_bounds__(1024) void loss_single_kernel(
    const float* __restrict__ out, const float* __restrict__ lb,
    const float* __restrict__ vel, const float* __restrict__ vfw,
    float* __restrict__ outw) {
  float mseN = 0.f, cnt = 0.f, k0 = 0.f, v0 = 0.f, dk = 0.f, dv = 0.f;
  for (int i = threadIdx.x; i < BT; i += 1024) {
    const int t = i & (Tn - 1);
    const float l = lb[i];
    const float m = (l != 0.0f) ? 1.0f : 0.0f;
    const float c = out[2 * BT + i];
    const float d = (c - l) * m;
    mseN += d * d;
    cnt += m;
    const float kc = out[i];
    const float vc = out[BT + i];
    if (t > 0) {
      const float kp = out[i - 1];
      const float vp = out[BT + i - 1];
      dk += (kc - kp) * (kc - kp);
      dv += (vc - vp) * (vc - vp);
    } else {
      const float a = vel[i] - kc;
      const float bb = vfw[i] - vc;
      k0 += a * a;
      v0 += bb * bb;
    }
  }
  float acc[6] = {mseN, cnt, k0, v0, dk, dv};
#pragma unroll
  for (int q = 0; q < 6; q++) {
#pragma unroll
    for (int mm = 1; mm < 64; mm <<= 1) acc[q] += __shfl_xor(acc[q], mm, 64);
  }
  __shared__ float red[16][6];
  if ((threadIdx.x & 63) == 0) {
#pragma unroll
    for (int q = 0; q < 6; q++) red[threadIdx.x >> 6][q] = acc[q];
  }
  __syncthreads();
  if (threadIdx.x == 0) {
    float s[6] = {0.f, 0.f, 0.f, 0.f, 0.f, 0.f};
    for (int w = 0; w < 16; w++)
#pragma unroll
      for (int q = 0; q < 6; q++) s[q] += red[w][q];
    finalize_loss(s, outw);
  }
}

extern "C" void kernel_launch(void* const* d_in, const int* in_sizes, int n_in,
                              void* d_out, int out_size, void* d_ws, size_t ws_size,
                              hipStream_t stream) {
  (void)in_sizes; (void)n_in; (void)out_size;
  const float* cont = (const float*)d_in[0];
  const int* cat = (const int*)d_in[1];
  const float* lb = (const float*)d_in[2];
  const float* dose = (const float*)d_in[3];
  const float* tdp = (const float*)d_in[4];
  const float* vfw = (const float*)d_in[5];   // v_from_weight
  const float* vel = (const float*)d_in[6];   // vanco_el
  const float* emb = (const float*)d_in[7];
  const float* W_ih = (const float*)d_in[8];
  const float* W_hh = (const float*)d_in[9];
  const float* b_ih = (const float*)d_in[10];
  const float* b_hh = (const float*)d_in[11];
  const float* W_out = (const float*)d_in[12];
  const float* b_out = (const float*)d_in[13];
  float* out = (float*)d_out;

  const bool fuse = (d_ws != nullptr) && (ws_size >= (size_t)Bn * 6 * sizeof(float));
  if (fuse) {
    float* part = (float*)d_ws;
    rnn_kernel<true><<<Bn / 4, 256, 0, stream>>>(cont, cat, lb, dose, tdp, emb, W_ih,
                                                 W_hh, b_ih, b_hh, W_out, b_out, vel,
                                                 vfw, part, out);
    loss_final2_kernel<<<1, 256, 0, stream>>>(part, out);
  } else {
    rnn_kernel<false><<<Bn / 4, 256, 0, stream>>>(cont, cat, lb, dose, tdp, emb, W_ih,
                                                  W_hh, b_ih, b_hh, W_out, b_out, vel,
                                                  vfw, nullptr, out);
    loss_single_kernel<<<1, 1024, 0, stream>>>(out, lb, vel, vfw, out);
  }
}

// Round 15
// 206.928 us; speedup vs baseline: 1.1710x; 1.1710x over previous
//
#include <hip/hip_runtime.h>

// PK_RNN: GRU + pharmacokinetic scan, B=2048 x T=256, HID=32.
// Round 14: base = round-12 green (230.2us total, the best; 64 lanes/batch,
// column-split packed-f32x2 gate dots, shfl_xor gate swaps, DPP kv reduce).
// Round-13's loss fusion reverted (+12us: anything added to the step body
// lengthens the serial chain). Single change: vfb REASSOCIATION -- the
// concn(t-1)-dependent vfb term is added AFTER the gate swap_adds (wv weights
// now full-value on both halves; vfb is lane-uniform so post-swap add is
// identical math). Removes the ds_bpermute from the concn->gate critical
// chain; the swaps now consume only early-available x/h partials.

constexpr int Bn = 2048, Tn = 256;
constexpr int HID = 32, CONT = 40, EMB = 8;
constexpr int VOCAB = 829, CODES = 32;
constexpr int BT = Bn * Tn;
constexpr int LOSS_BLOCKS = 256;

typedef float f32x2 __attribute__((ext_vector_type(2)));

__device__ __forceinline__ float frcp(float x) { return __builtin_amdgcn_rcpf(x); }

// lane j gets (its value + partner(j^32)'s value) -- proven green primitive
__device__ __forceinline__ float swap_add(float x) {
  return x + __shfl_xor(x, 32, 64);
}

// x + dpp_shifted(x), old=0, all rows/banks enabled, bound_ctrl=1 (0-fill)
template <int CTRL>
__device__ __forceinline__ float dpp_add(float x) {
  int y = __builtin_amdgcn_update_dpp(0, __float_as_int(x), CTRL, 0xf, 0xf, true);
  return x + __int_as_float(y);
}

// ---------------- recurrent kernel ----------------
__global__ __launch_bounds__(256, 2) void rnn_kernel(
    const float* __restrict__ cont, const int* __restrict__ cat,
    const float* __restrict__ lb, const float* __restrict__ dose,
    const float* __restrict__ tdp, const float* __restrict__ embed,
    const float* __restrict__ W_ih, const float* __restrict__ W_hh,
    const float* __restrict__ b_ih, const float* __restrict__ b_hh,
    const float* __restrict__ W_out, const float* __restrict__ b_out,
    float* __restrict__ out) {
  __shared__ __attribute__((aligned(16))) float esh[VOCAB * EMB];  // 26528 B
  __shared__ __attribute__((aligned(16))) float ebl[4][64][EMB];   //  8192 B
  __shared__ __attribute__((aligned(16))) float hsh[4][HID];       //   512 B

  const int tid = threadIdx.x;
  const int wv = tid >> 6;    // wave id in block = batch-in-block 0..3
  const int j = tid & 63;     // lane
  const int u = j & 31;       // hidden unit owned by this lane
  const int half = j >> 5;    // column-half this lane covers
  const int b = blockIdx.x * 4 + wv;
  const int base = b * Tn;

  // embedding table -> LDS (once); only cross-wave shared data
  for (int i = tid; i < VOCAB * EMB; i += 256) esh[i] = embed[i];
  __syncthreads();

  // ---- loop-invariant weights into registers (packed as f32x2 pairs) ----
  f32x2 wxr2[12], wxz2[12], wxn2[12];
  {
    float tr[24], tz[24], tn_[24];
    const float* Wr = W_ih + (size_t)u * 49;
    const float* Wz = W_ih + (size_t)(HID + u) * 49;
    const float* Wn = W_ih + (size_t)(2 * HID + u) * 49;
    const int eo = half * 4;
    const int co = 8 + half * 20;
#pragma unroll
    for (int k = 0; k < 4; k++) { tr[k] = Wr[eo + k]; tz[k] = Wz[eo + k]; tn_[k] = Wn[eo + k]; }
#pragma unroll
    for (int k = 0; k < 20; k++) {
      tr[4 + k] = Wr[co + k]; tz[4 + k] = Wz[co + k]; tn_[4 + k] = Wn[co + k];
    }
#pragma unroll
    for (int k = 0; k < 12; k++) {
      wxr2[k] = (f32x2){tr[2 * k], tr[2 * k + 1]};
      wxz2[k] = (f32x2){tz[2 * k], tz[2 * k + 1]};
      wxn2[k] = (f32x2){tn_[2 * k], tn_[2 * k + 1]};
    }
  }
  // vfb weights: FULL value on BOTH halves (vfb term added post-swap, once per lane)
  const float wvr = W_ih[(size_t)u * 49 + 48];
  const float wvz = W_ih[(size_t)(HID + u) * 49 + 48];
  const float wvn = W_ih[(size_t)(2 * HID + u) * 49 + 48];
  f32x2 whr2[8], whz2[8], whn2[8];
#pragma unroll
  for (int k = 0; k < 8; k++) {
    whr2[k] = (f32x2){W_hh[(size_t)u * HID + half * 16 + 2 * k],
                      W_hh[(size_t)u * HID + half * 16 + 2 * k + 1]};
    whz2[k] = (f32x2){W_hh[(size_t)(HID + u) * HID + half * 16 + 2 * k],
                      W_hh[(size_t)(HID + u) * HID + half * 16 + 2 * k + 1]};
    whn2[k] = (f32x2){W_hh[(size_t)(2 * HID + u) * HID + half * 16 + 2 * k],
                      W_hh[(size_t)(2 * HID + u) * HID + half * 16 + 2 * k + 1]};
  }
  const float br = half ? 0.0f : (b_ih[u] + b_hh[u]);
  const float bz = half ? 0.0f : (b_ih[HID + u] + b_hh[HID + u]);
  const float bni = half ? 0.0f : b_ih[2 * HID + u];
  const float bnh = half ? 0.0f : b_hh[2 * HID + u];
  const float wkv = W_out[half * HID + u];
  const float bo0 = b_out[0], bo1 = b_out[1];

  hsh[wv][u] = 0.0f;
  float hj = 0.0f, tm = 0.0f, concn = 0.0f;
  float td_c = tdp[base], d_c = dose[base], lbp_c = 0.0f;

  // cont slice double buffer: 5 float4 = 20 floats at offset half*20
  float4 xA[5], xB[5];
  {
    const float4* c4 = reinterpret_cast<const float4*>(cont + (size_t)base * CONT + half * 20);
#pragma unroll
    for (int q = 0; q < 5; q++) xA[q] = c4[q];
  }

#define STEP(XC, XN, TT)                                                          \
  {                                                                               \
    const int t = (TT);                                                           \
    const int tn = (t + 1 < Tn) ? (t + 1) : t;                                    \
    /* (1) LDS reads first: e, then the 4 h reads */                              \
    const float4 e = *reinterpret_cast<const float4*>(&ebl[wv][t & 63][half * 4]);\
    const float4* h4 = reinterpret_cast<const float4*>(&hsh[wv][half * 16]);      \
    const float4 hv0 = h4[0];                                                     \
    const float4 hv1 = h4[1];                                                     \
    const float4 hv2 = h4[2];                                                     \
    const float4 hv3 = h4[3];                                                     \
    /* (2) global prefetches for t+1 */                                           \
    { const float4* c4 = reinterpret_cast<const float4*>(                         \
          cont + (size_t)(base + tn) * CONT + half * 20);                         \
      _Pragma("unroll") for (int q = 0; q < 5; q++) XN[q] = c4[q]; }              \
    const float td_n = tdp[base + tn];                                            \
    const float d_n = dose[base + tn];                                            \
    const float lbp_n = lb[base + tn - 1];                                        \
    /* (3) x-dots, f32x2-packed (v_pk_fma_f32) -- NO vfb term here */             \
    f32x2 arv, azv, anv;                                                          \
    {                                                                             \
      const f32x2 e01 = (f32x2){e.x, e.y}, e23 = (f32x2){e.z, e.w};               \
      arv = wxr2[0] * e01 + wxr2[1] * e23;                                        \
      azv = wxz2[0] * e01 + wxz2[1] * e23;                                        \
      anv = wxn2[0] * e01 + wxn2[1] * e23;                                        \
      _Pragma("unroll") for (int q = 0; q < 5; q++) {                             \
        const float4 xv = XC[q];                                                  \
        const f32x2 x01 = (f32x2){xv.x, xv.y}, x23 = (f32x2){xv.z, xv.w};         \
        arv += wxr2[2 + 2 * q] * x01; arv += wxr2[3 + 2 * q] * x23;               \
        azv += wxz2[2 + 2 * q] * x01; azv += wxz2[3 + 2 * q] * x23;               \
        anv += wxn2[2 + 2 * q] * x01; anv += wxn2[3 + 2 * q] * x23;               \
      }                                                                           \
    }                                                                             \
    /* (4) h-dots, f32x2-packed */                                                \
    f32x2 grv, gzv, gnv;                                                          \
    {                                                                             \
      const f32x2 h01 = (f32x2){hv0.x, hv0.y}, h23 = (f32x2){hv0.z, hv0.w};       \
      const f32x2 h45 = (f32x2){hv1.x, hv1.y}, h67 = (f32x2){hv1.z, hv1.w};       \
      const f32x2 h89 = (f32x2){hv2.x, hv2.y}, hab = (f32x2){hv2.z, hv2.w};       \
      const f32x2 hcd = (f32x2){hv3.x, hv3.y}, hef = (f32x2){hv3.z, hv3.w};       \
      grv = whr2[0] * h01 + whr2[1] * h23;                                        \
      gzv = whz2[0] * h01 + whz2[1] * h23;                                        \
      gnv = whn2[0] * h01 + whn2[1] * h23;                                        \
      grv += whr2[2] * h45; grv += whr2[3] * h67;                                 \
      gzv += whz2[2] * h45; gzv += whz2[3] * h67;                                 \
      gnv += whn2[2] * h45; gnv += whn2[3] * h67;                                 \
      grv += whr2[4] * h89; grv += whr2[5] * hab;                                 \
      gzv += whz2[4] * h89; gzv += whz2[5] * hab;                                 \
      gnv += whn2[4] * h89; gnv += whn2[5] * hab;                                 \
      grv += whr2[6] * hcd; grv += whr2[7] * hef;                                 \
      gzv += whz2[6] * hcd; gzv += whz2[7] * hef;                                 \
      gnv += whn2[6] * hcd; gnv += whn2[7] * hef;                                 \
    }                                                                             \
    const float ar = arv.x + arv.y;                                               \
    const float az = azv.x + azv.y;                                               \
    const float an = anv.x + anv.y;                                               \
    const float gr = grv.x + grv.y;                                               \
    const float gz = gzv.x + gzv.y;                                               \
    const float gn = gnv.x + gnv.y;                                               \
    /* (5) swaps on early-available partials (OFF the concn chain) */             \
    const float sr0 = swap_add(ar + gr + br);                                     \
    const float sz0 = swap_add(az + gz + bz);                                     \
    const float sa0 = swap_add(an + bni);                                         \
    const float sg = swap_add(gn + bnh);                                          \
    /* (6) vfb term added POST-swap: concn->gate chain skips the bpermute */      \
    const float fmv = (lbp_c != 0.0f) ? 1.0f : 0.0f;                              \
    const float vfb = concn * (1.0f - fmv) + lbp_c * fmv;                         \
    const float sr = sr0 + vfb * wvr;                                             \
    const float sz = sz0 + vfb * wvz;                                             \
    const float sa = sa0 + vfb * wvn;                                             \
    const float r = frcp(1.0f + __expf(-sr));                                     \
    const float z = frcp(1.0f + __expf(-sz));                                     \
    const float pre = sa + r * sg;                                                \
    const float nv = 1.0f - 2.0f * frcp(__expf(2.0f * pre) + 1.0f);               \
    const float h2 = (1.0f - z) * nv + z * hj;                                    \
    hsh[wv][u] = h2;                                                              \
    hj = h2;                                                                      \
    /* kv reduce: DPP intra-32 tree + readlane broadcasts */                      \
    float s = h2 * wkv;                                                           \
    s = dpp_add<0x111>(s); /* row_shr:1 */                                        \
    s = dpp_add<0x112>(s); /* row_shr:2 */                                        \
    s = dpp_add<0x114>(s); /* row_shr:4 */                                        \
    s = dpp_add<0x118>(s); /* row_shr:8 */                                        \
    s = dpp_add<0x142>(s); /* row_bcast:15 -> lane31=sum(0:32), lane63=sum(32:64) */ \
    const float pk_s = __int_as_float(__builtin_amdgcn_readlane(__float_as_int(s), 31)); \
    const float pv_s = __int_as_float(__builtin_amdgcn_readlane(__float_as_int(s), 63)); \
    const float kk = __expf(pk_s + bo0);                                          \
    const float vv = __expf(pv_s + bo1);                                          \
    const float Aa = __expf(-kk * td_c);                                          \
    const float eD = __expf(-kk * d_c);                                           \
    const float Bq = frcp(kk) * (1.0f - eD) * __expf(-kk * (td_c - d_c));         \
    tm = tm * Aa + Bq;                                                            \
    concn = tm * frcp(vv + 1e-6f);                                                \
    if (j < 3) {                                                                  \
      const float val = (j == 0) ? kk : ((j == 1) ? vv : concn);                  \
      out[j * BT + base + t] = val;                                               \
    }                                                                             \
    td_c = td_n;                                                                  \
    d_c = d_n;                                                                    \
    lbp_c = lbp_n;                                                                \
  }

  for (int ch = 0; ch < Tn / 64; ++ch) {
    {  // per-wave embedding presum for this 64-step chunk: lane j handles t=ch*64+j
      const int4* cp4 =
          reinterpret_cast<const int4*>(cat + ((size_t)(base + ch * 64 + j)) * CODES);
      float a0 = 0.f, a1 = 0.f, a2 = 0.f, a3 = 0.f;
      float a4 = 0.f, a5 = 0.f, a6 = 0.f, a7 = 0.f;
#pragma unroll
      for (int q = 0; q < 8; q++) {
        const int4 c4 = cp4[q];
        {
          const float4* er = reinterpret_cast<const float4*>(esh + c4.x * EMB);
          const float4 r0 = er[0], r1 = er[1];
          a0 += r0.x; a1 += r0.y; a2 += r0.z; a3 += r0.w;
          a4 += r1.x; a5 += r1.y; a6 += r1.z; a7 += r1.w;
        }
        {
          const float4* er = reinterpret_cast<const float4*>(esh + c4.y * EMB);
          const float4 r0 = er[0], r1 = er[1];
          a0 += r0.x; a1 += r0.y; a2 += r0.z; a3 += r0.w;
          a4 += r1.x; a5 += r1.y; a6 += r1.z; a7 += r1.w;
        }
        {
          const float4* er = reinterpret_cast<const float4*>(esh + c4.z * EMB);
          const float4 r0 = er[0], r1 = er[1];
          a0 += r0.x; a1 += r0.y; a2 += r0.z; a3 += r0.w;
          a4 += r1.x; a5 += r1.y; a6 += r1.z; a7 += r1.w;
        }
        {
          const float4* er = reinterpret_cast<const float4*>(esh + c4.w * EMB);
          const float4 r0 = er[0], r1 = er[1];
          a0 += r0.x; a1 += r0.y; a2 += r0.z; a3 += r0.w;
          a4 += r1.x; a5 += r1.y; a6 += r1.z; a7 += r1.w;
        }
      }
      *reinterpret_cast<float4*>(&ebl[wv][j][0]) = make_float4(a0, a1, a2, a3);
      *reinterpret_cast<float4*>(&ebl[wv][j][4]) = make_float4(a4, a5, a6, a7);
    }
    __syncthreads();  // ordering insurance for presum -> STEP reads (4 total)
#pragma unroll 1
    for (int tl = 0; tl < 64; tl += 2) {
      STEP(xA, xB, ch * 64 + tl);
      STEP(xB, xA, ch * 64 + tl + 1);
    }
  }
#undef STEP
}

// ---------------- loss reduction (deterministic, two-stage, 6KB ws) ----------------
__global__ __launch_bounds__(256) void loss_partial_kernel(
    const float* __restrict__ out, const float* __restrict__ lb,
    const float* __restrict__ vel, const float* __restrict__ vfw,
    float* __restrict__ part) {
  float mseN = 0.f, cnt = 0.f, k0 = 0.f, v0 = 0.f, dk = 0.f, dv = 0.f;
  for (int i = blockIdx.x * 256 + threadIdx.x; i < BT; i += LOSS_BLOCKS * 256) {
    const int t = i & (Tn - 1);
    const float l = lb[i];
    const float m = (l != 0.0f) ? 1.0f : 0.0f;
    const float c = out[2 * BT + i];
    const float d = (c - l) * m;
    mseN += d * d;
    cnt += m;
    const float kc = out[i];
    const float vc = out[BT + i];
    if (t > 0) {
      const float kp = out[i - 1];
      const float vp = out[BT + i - 1];
      dk += (kc - kp) * (kc - kp);
      dv += (vc - vp) * (vc - vp);
    } else {
      const float a = vel[i] - kc;
      const float bb = vfw[i] - vc;
      k0 += a * a;
      v0 += bb * bb;
    }
  }
  float acc[6] = {mseN, cnt, k0, v0, dk, dv};
#pragma unroll
  for (int q = 0; q < 6; q++) {
#pragma unroll
    for (int mm = 1; mm < 64; mm <<= 1) acc[q] += __shfl_xor(acc[q], mm, 64);
  }
  __shared__ float red[4][6];
  if ((threadIdx.x & 63) == 0) {
#pragma unroll
    for (int q = 0; q < 6; q++) red[threadIdx.x >> 6][q] = acc[q];
  }
  __syncthreads();
  if (threadIdx.x == 0) {
#pragma unroll
    for (int q = 0; q < 6; q++)
      part[blockIdx.x * 6 + q] = red[0][q] + red[1][q] + red[2][q] + red[3][q];
  }
}

__device__ __forceinline__ void finalize_loss(const float s[6], float* out) {
  const float mse = s[0] / s[1];
  const float loss = mse + (s[2] / (float)Bn) * 1000.0f + (s[3] / (float)Bn) * 1000.0f +
                     (s[4] / (float)(Bn * (Tn - 1))) * 1000.0f +
                     (s[5] / (float)(Bn * (Tn - 1))) * 1000.0f;
  out[3 * BT] = loss;
  out[3 * BT + 1] = mse;
}

__global__ __launch_bounds__(256) void loss_final_kernel(const float* __restrict__ part,
                                                         float* __restrict__ out) {
  float acc[6] = {0.f, 0.f, 0.f, 0.f, 0.f, 0.f};
  for (int i = threadIdx.x; i < LOSS_BLOCKS; i += 256) {
#pragma unroll
    for (int q = 0; q < 6; q++) acc[q] += part[i * 6 + q];
  }
#pragma unroll
  for (int q = 0; q < 6; q++) {
#pragma unroll
    for (int mm = 1; mm < 64; mm <<= 1) acc[q] += __shfl_xor(acc[q], mm, 64);
  }
  __shared__ float red[4][6];
  if ((threadIdx.x & 63) == 0) {
#pragma unroll
    for (int q = 0; q < 6; q++) red[threadIdx.x >> 6][q] = acc[q];
  }
  __syncthreads();
  if (threadIdx.x == 0) {
    float s[6];
#pragma unroll
    for (int q = 0; q < 6; q++) s[q] = red[0][q] + red[1][q] + red[2][q] + red[3][q];
    finalize_loss(s, out);
  }
}

// ws-free fallback: one block does the whole reduction (safety net only)
__global__ __launch_bounds__(1024) void loss_single_kernel(
    const float* __restrict__ out, const float* __restrict__ lb,
    const float* __restrict__ vel, const float* __restrict__ vfw,
    float* __restrict__ outw) {
  float mseN = 0.f, cnt = 0.f, k0 = 0.f, v0 = 0.f, dk = 0.f, dv = 0.f;
  for (int i = threadIdx.x; i < BT; i += 1024) {
    const int t = i & (Tn - 1);
    const float l = lb[i];
    const float m = (l != 0.0f) ? 1.0f : 0.0f;
    const float c = out[2 * BT + i];
    const float d = (c - l) * m;
    mseN += d * d;
    cnt += m;
    const float kc = out[i];
    const float vc = out[BT + i];
    if (t > 0) {
      const float kp = out[i - 1];
      const float vp = out[BT + i - 1];
      dk += (kc - kp) * (kc - kp);
      dv += (vc - vp) * (vc - vp);
    } else {
      const float a = vel[i] - kc;
      const float bb = vfw[i] - vc;
      k0 += a * a;
      v0 += bb * bb;
    }
  }
  float acc[6] = {mseN, cnt, k0, v0, dk, dv};
#pragma unroll
  for (int q = 0; q < 6; q++) {
#pragma unroll
    for (int mm = 1; mm < 64; mm <<= 1) acc[q] += __shfl_xor(acc[q], mm, 64);
  }
  __shared__ float red[16][6];
  if ((threadIdx.x & 63) == 0) {
#pragma unroll
    for (int q = 0; q < 6; q++) red[threadIdx.x >> 6][q] = acc[q];
  }
  __syncthreads();
  if (threadIdx.x == 0) {
    float s[6] = {0.f, 0.f, 0.f, 0.f, 0.f, 0.f};
    for (int w = 0; w < 16; w++)
#pragma unroll
      for (int q = 0; q < 6; q++) s[q] += red[w][q];
    finalize_loss(s, outw);
  }
}

extern "C" void kernel_launch(void* const* d_in, const int* in_sizes, int n_in,
                              void* d_out, int out_size, void* d_ws, size_t ws_size,
                              hipStream_t stream) {
  (void)in_sizes; (void)n_in; (void)out_size;
  const float* cont = (const float*)d_in[0];
  const int* cat = (const int*)d_in[1];
  const float* lb = (const float*)d_in[2];
  const float* dose = (const float*)d_in[3];
  const float* tdp = (const float*)d_in[4];
  const float* vfw = (const float*)d_in[5];   // v_from_weight
  const float* vel = (const float*)d_in[6];   // vanco_el
  const float* emb = (const float*)d_in[7];
  const float* W_ih = (const float*)d_in[8];
  const float* W_hh = (const float*)d_in[9];
  const float* b_ih = (const float*)d_in[10];
  const float* b_hh = (const float*)d_in[11];
  const float* W_out = (const float*)d_in[12];
  const float* b_out = (const float*)d_in[13];
  float* out = (float*)d_out;

  rnn_kernel<<<Bn / 4, 256, 0, stream>>>(cont, cat, lb, dose, tdp, emb, W_ih, W_hh,
                                         b_ih, b_hh, W_out, b_out, out);

  if (d_ws != nullptr && ws_size >= (size_t)LOSS_BLOCKS * 6 * sizeof(float)) {
    float* part = (float*)d_ws;
    loss_partial_kernel<<<LOSS_BLOCKS, 256, 0, stream>>>(out, lb, vel, vfw, part);
    loss_final_kernel<<<1, 256, 0, stream>>>(part, out);
  } else {
    loss_single_kernel<<<1, 1024, 0, stream>>>(out, lb, vel, vfw, out);
  }
}